// Round 1
// baseline (343.016 us; speedup 1.0000x reference)
//
#include <hip/hip_runtime.h>
#include <math.h>

// Problem constants
#define LQ 512
#define NH 12
#define ND 384
#define PAIRC 128
#define RSQRT3 0.5773502691896258f
// sq scale: (1/4)*(1/sqrt(3))
#define SQSCALE 0.1443375672974065f
// point coef: 0.5/sqrt(18)/sqrt(3) = 0.5/sqrt(54)
#define PTCOEF 0.06804138174397717f

__device__ __forceinline__ float dot4(float4 a, float4 b){
  return a.x*b.x + a.y*b.y + a.z*b.z + a.w*b.w;
}
__device__ __forceinline__ float wred_max(float v){
  #pragma unroll
  for (int o = 32; o > 0; o >>= 1) v = fmaxf(v, __shfl_xor(v, o));
  return v;
}
__device__ __forceinline__ float wred_sum(float v){
  #pragma unroll
  for (int o = 32; o > 0; o >>= 1) v += __shfl_xor(v, o);
  return v;
}

// ---------------------------------------------------------------------------
// K1: projections. Per (head, 32-l tile) block: GEMM node(32x384) x W(384x96)
// ch map: 0..15 sq | 16..31 sk | 32..47 sv | 48..59 pq | 60..71 pk | 72..95 pv
// Point channels get rotated by R[l] and translated by t[l] before store.
// ---------------------------------------------------------------------------
__global__ __launch_bounds__(256) void k1_proj(
    const float* __restrict__ node, const float* __restrict__ Rm, const float* __restrict__ tv,
    const float* __restrict__ sq_k, const float* __restrict__ sk_k, const float* __restrict__ sv_k,
    const float* __restrict__ pq_k, const float* __restrict__ pk_k, const float* __restrict__ pv_k,
    float* __restrict__ sq_o, float* __restrict__ sk_o, float* __restrict__ sv_o,
    float* __restrict__ pq_o, float* __restrict__ pk_o, float* __restrict__ pv_o)
{
  const int h  = blockIdx.x;
  const int l0 = blockIdx.y * 32;
  const int tid = threadIdx.x;
  const int tl = tid & 15;       // 16 groups -> 2 l each
  const int tc = tid >> 4;       // 16 groups -> 6 ch each
  const int ch0 = tc * 6;

  __shared__ float nl[32*33];    // node tile [l][k], stride 33
  __shared__ float wl[32*97];    // W tile [k][ch], stride 97

  float acc0[6] = {0,0,0,0,0,0};
  float acc1[6] = {0,0,0,0,0,0};
  const float4* node4 = (const float4*)node;

  for (int kt = 0; kt < 12; ++kt) {
    const int k0 = kt * 32;
    __syncthreads();
    { // stage node tile: 32 rows x 8 float4 = 256 float4 (one per thread)
      int l = tid >> 3, k4 = tid & 7;
      float4 v = node4[(size_t)(l0 + l)*96 + kt*8 + k4];
      float* d = &nl[l*33 + 4*k4];
      d[0]=v.x; d[1]=v.y; d[2]=v.z; d[3]=v.w;
    }
    // stage W tile: 32 x 96 gathered from the six projection arrays
    for (int e = tid; e < 3072; e += 256) {
      int k = e / 96, ch = e - k*96;
      float val;
      if (ch < 48) {
        const float* s = (ch < 16) ? sq_k : (ch < 32 ? sk_k : sv_k);
        val = s[((size_t)h*ND + k0 + k)*16 + (ch & 15)];
      } else if (ch < 72) {
        const float* s = (ch < 60) ? pq_k : pk_k;
        int col = ch - (ch < 60 ? 48 : 60);
        val = s[((size_t)h*ND + k0 + k)*12 + col];
      } else {
        val = pv_k[((size_t)h*ND + k0 + k)*24 + (ch - 72)];
      }
      wl[k*97 + ch] = val;
    }
    __syncthreads();
    for (int k = 0; k < 32; ++k) {
      float n0 = nl[(2*tl  )*33 + k];
      float n1 = nl[(2*tl+1)*33 + k];
      #pragma unroll
      for (int j = 0; j < 6; ++j) {
        float w = wl[k*97 + ch0 + j];
        acc0[j] += n0 * w;
        acc1[j] += n1 * w;
      }
    }
  }

  // post-process + store
  #pragma unroll
  for (int i = 0; i < 2; ++i) {
    const float* ac = i ? acc1 : acc0;
    const int l = l0 + 2*tl + i;
    if (ch0 < 48) {
      #pragma unroll
      for (int j = 0; j < 6; ++j) {
        int ch = ch0 + j; float v = ac[j];
        if (ch < 16)      sq_o[((size_t)h*LQ + l)*16 + ch       ] = v * SQSCALE;
        else if (ch < 32) sk_o[((size_t)h*LQ + l)*16 + (ch - 16)] = v;
        else              sv_o[((size_t)h*LQ + l)*16 + (ch - 32)] = v;
      }
    } else {
      float R_[9], t_[3];
      #pragma unroll
      for (int q = 0; q < 9; ++q) R_[q] = Rm[(size_t)l*9 + q];
      #pragma unroll
      for (int q = 0; q < 3; ++q) t_[q] = tv[(size_t)l*3 + q];
      #pragma unroll
      for (int b = 0; b < 6; b += 3) {
        int chb = ch0 + b;
        float x = ac[b], y = ac[b+1], z = ac[b+2];
        float g0 = x*R_[0] + y*R_[1] + z*R_[2] + t_[0];
        float g1 = x*R_[3] + y*R_[4] + z*R_[5] + t_[1];
        float g2 = x*R_[6] + y*R_[7] + z*R_[8] + t_[2];
        if (chb < 60) {
          size_t base = ((size_t)h*LQ + l)*12 + (chb - 48);
          pq_o[base] = g0; pq_o[base+1] = g1; pq_o[base+2] = g2;
        } else if (chb < 72) {
          size_t base = ((size_t)h*LQ + l)*12 + (chb - 60);
          pk_o[base] = g0; pk_o[base+1] = g1; pk_o[base+2] = g2;
        } else {
          size_t base = ((size_t)h*LQ + l)*24 + (chb - 72);
          pv_o[base] = g0; pv_o[base+1] = g1; pv_o[base+2] = g2;
        }
      }
    }
  }
}

// ---------------------------------------------------------------------------
// K2: flash-style IPA attention. One block per query row n; 4 waves; wave w
// owns heads 3w..3w+2 (softmax state stays wave-local). pairwise tile
// 64 x 128 f32 staged in LDS as float4 with XOR-swizzled columns.
// Output channels per head (float4 units): 0..31 pairwise | 32..35 sv | 36..41 pv
// res layout per head (176): [scaler 16][pairwise 128][po_local 24][norm 8]
// ---------------------------------------------------------------------------
__global__ __launch_bounds__(256) void k2_attn(
    const float* __restrict__ pairwise, const float* __restrict__ Rm, const float* __restrict__ tv,
    const float* __restrict__ pr_k, const float* __restrict__ point_weight,
    const float* __restrict__ sq_w, const float* __restrict__ sk_w, const float* __restrict__ sv_w,
    const float* __restrict__ pq_w, const float* __restrict__ pk_w, const float* __restrict__ pv_w,
    float* __restrict__ res_w)
{
  const int n = blockIdx.x;
  const int tid = threadIdx.x;
  const int lane = tid & 63, wave = tid >> 6;

  __shared__ float4 pwt4[64*32];                  // 32 KB pairwise tile (swizzled)
  __shared__ float Et[4][3][64];                  // exp values per wave/head/m
  __shared__ __align__(16) float sq_s[12*16];
  __shared__ __align__(16) float pq_s[12*12];
  __shared__ __align__(16) float pr_s[12*128];
  __shared__ float pqn_s[12], cpw_s[12];
  __shared__ __align__(16) float res_s[12*176];
  __shared__ float pot_s[12*24];
  __shared__ float tn[3], Rn[9];

  // ---- init ----
  for (int e = tid; e < 192; e += 256)
    sq_s[e] = sq_w[((size_t)(e>>4)*LQ + n)*16 + (e & 15)];
  for (int e = tid; e < 144; e += 256)
    pq_s[e] = pq_w[((size_t)(e/12)*LQ + n)*12 + (e % 12)];
  for (int e = tid; e < 1536; e += 256)
    pr_s[e] = pr_k[e] * RSQRT3;
  if (tid < 12) {
    float x = point_weight[tid];
    float sp = (x > 20.f) ? x : log1pf(__expf(x));
    cpw_s[tid] = sp * PTCOEF;
  }
  if (tid < 3) tn[tid] = tv[(size_t)n*3 + tid];
  if (tid < 9) Rn[tid] = Rm[(size_t)n*9 + tid];
  __syncthreads();
  if (tid < 12) {
    float s = 0.f;
    #pragma unroll
    for (int c = 0; c < 12; ++c) { float v = pq_s[tid*12 + c]; s += v*v; }
    pqn_s[tid] = s;
  }

  float Mreg[3] = {-INFINITY, -INFINITY, -INFINITY};
  float Sreg[3] = {0.f, 0.f, 0.f};

  // output slots: slot s in [0,126) -> (head_local = s/42, c4 = s%42)
  const int hl0 = lane / 42, c40 = lane - hl0*42;
  const int s1 = lane + 64;
  const bool act1 = (s1 < 126);
  const int hl1 = act1 ? s1/42 : 0, c41 = act1 ? (s1 - hl1*42) : 0;
  const int h0n = wave*3 + hl0, h1n = wave*3 + hl1;
  float4 acc0 = {0,0,0,0}, acc1 = {0,0,0,0};

  const float4* sv4  = (const float4*)sv_w;
  const float4* pv4  = (const float4*)pv_w;
  const float4* pr4  = (const float4*)pr_s;
  const float4* sq4  = (const float4*)sq_s;
  const float4* pw4g = (const float4*)pairwise;

  const float4* gb0 = 0; int gs0 = 0;
  if (c40 >= 36)      { gb0 = pv4 + (size_t)h0n*LQ*6 + (c40 - 36); gs0 = 6; }
  else if (c40 >= 32) { gb0 = sv4 + (size_t)h0n*LQ*4 + (c40 - 32); gs0 = 4; }
  const float4* gb1 = 0; int gs1 = 0;
  if (act1) {
    if (c41 >= 36)      { gb1 = pv4 + (size_t)h1n*LQ*6 + (c41 - 36); gs1 = 6; }
    else if (c41 >= 32) { gb1 = sv4 + (size_t)h1n*LQ*4 + (c41 - 32); gs1 = 4; }
  }

  for (int mt = 0; mt < 8; ++mt) {
    const int m0 = mt * 64;
    __syncthreads();   // previous tile fully consumed (and init visible at mt=0)
    // ---- stage pairwise tile (swizzled float4 columns) ----
    #pragma unroll
    for (int i = 0; i < 8; ++i) {
      int e4 = i*256 + tid;
      int m = e4 >> 5, c4 = e4 & 31;
      float4 v = pw4g[((size_t)n*LQ + m0 + m)*32 + c4];
      pwt4[(m << 5) | (c4 ^ (m & 31))] = v;
    }
    __syncthreads();

    // ---- logits for m = m0 + lane (3 heads per wave) ----
    const int mm = m0 + lane;
    const int key = lane & 31;
    float prd0 = 0.f, prd1 = 0.f, prd2 = 0.f;
    #pragma unroll 4
    for (int c = 0; c < 32; ++c) {
      float4 p = pwt4[(lane << 5) | (c ^ key)];
      prd0 += dot4(p, pr4[(wave*3+0)*32 + c]);
      prd1 += dot4(p, pr4[(wave*3+1)*32 + c]);
      prd2 += dot4(p, pr4[(wave*3+2)*32 + c]);
    }
    float lgt[3];
    #pragma unroll
    for (int j = 0; j < 3; ++j) {
      const int h = wave*3 + j;
      const float4* skp = (const float4*)(sk_w + ((size_t)h*LQ + mm)*16);
      float sd = 0.f;
      #pragma unroll
      for (int q = 0; q < 4; ++q) sd += dot4(sq4[h*4 + q], skp[q]);
      const float4* pkp = (const float4*)(pk_w + ((size_t)h*LQ + mm)*12);
      const float4* pqp = (const float4*)(pq_s + h*12);
      float pd = 0.f, pkn = 0.f;
      #pragma unroll
      for (int q = 0; q < 3; ++q) {
        float4 a = pqp[q], b = pkp[q];
        pd  += dot4(a, b);
        pkn += dot4(b, b);
      }
      float prd = (j == 0) ? prd0 : (j == 1 ? prd1 : prd2);
      lgt[j] = sd + prd - cpw_s[h]*(pqn_s[h] + pkn - 2.f*pd);
    }

    // ---- online softmax update (wave-local) ----
    float scl[3];
    #pragma unroll
    for (int j = 0; j < 3; ++j) {
      float tm = wred_max(lgt[j]);
      float Mn = fmaxf(Mreg[j], tm);
      float e  = __expf(lgt[j] - Mn);
      float ts = wred_sum(e);
      scl[j] = __expf(Mreg[j] - Mn);
      Sreg[j] = Sreg[j]*scl[j] + ts;
      Mreg[j] = Mn;
      Et[wave][j][lane] = e;
    }

    // ---- accumulate outputs ----
    float sc0 = (hl0 == 0) ? scl[0] : (hl0 == 1 ? scl[1] : scl[2]);
    acc0.x *= sc0; acc0.y *= sc0; acc0.z *= sc0; acc0.w *= sc0;
    float sc1 = (hl1 == 0) ? scl[0] : (hl1 == 1 ? scl[1] : scl[2]);
    if (act1) { acc1.x *= sc1; acc1.y *= sc1; acc1.z *= sc1; acc1.w *= sc1; }

    for (int m = 0; m < 64; ++m) {
      float e0 = Et[wave][hl0][m];
      float4 v0;
      if (c40 < 32) v0 = pwt4[(m << 5) | (c40 ^ (m & 31))];
      else          v0 = gb0[(size_t)(m0 + m)*gs0];
      acc0.x += e0*v0.x; acc0.y += e0*v0.y; acc0.z += e0*v0.z; acc0.w += e0*v0.w;
      if (act1) {
        float e1 = Et[wave][hl1][m];
        float4 v1;
        if (c41 < 32) v1 = pwt4[(m << 5) | (c41 ^ (m & 31))];
        else          v1 = gb1[(size_t)(m0 + m)*gs1];
        acc1.x += e1*v1.x; acc1.y += e1*v1.y; acc1.z += e1*v1.z; acc1.w += e1*v1.w;
      }
    }
  }

  // ---- epilogue: normalize and assemble res ----
  {
    float Sv0 = (hl0 == 0) ? Sreg[0] : (hl0 == 1 ? Sreg[1] : Sreg[2]);
    float r = 1.f / Sv0;
    acc0.x *= r; acc0.y *= r; acc0.z *= r; acc0.w *= r;
    float* d;
    if (c40 < 32)      d = res_s + h0n*176 + 16 + 4*c40;
    else if (c40 < 36) d = res_s + h0n*176 + (c40 - 32)*4;
    else               d = pot_s + h0n*24  + (c40 - 36)*4;
    d[0] = acc0.x; d[1] = acc0.y; d[2] = acc0.z; d[3] = acc0.w;
  }
  if (act1) {
    float Sv1 = (hl1 == 0) ? Sreg[0] : (hl1 == 1 ? Sreg[1] : Sreg[2]);
    float r = 1.f / Sv1;
    acc1.x *= r; acc1.y *= r; acc1.z *= r; acc1.w *= r;
    float* d;
    if (c41 < 32)      d = res_s + h1n*176 + 16 + 4*c41;
    else if (c41 < 36) d = res_s + h1n*176 + (c41 - 32)*4;
    else               d = pot_s + h1n*24  + (c41 - 36)*4;
    d[0] = acc1.x; d[1] = acc1.y; d[2] = acc1.z; d[3] = acc1.w;
  }
  __syncthreads();
  // point outputs: subtract t[n], rotate to local frame with R[n]^T, norms
  if (tid < 96) {
    int h = tid >> 3, p = tid & 7;
    float v0 = pot_s[h*24 + p*3 + 0] - tn[0];
    float v1 = pot_s[h*24 + p*3 + 1] - tn[1];
    float v2 = pot_s[h*24 + p*3 + 2] - tn[2];
    float f0 = v0*Rn[0] + v1*Rn[3] + v2*Rn[6];
    float f1 = v0*Rn[1] + v1*Rn[4] + v2*Rn[7];
    float f2 = v0*Rn[2] + v1*Rn[5] + v2*Rn[8];
    res_s[h*176 + 144 + p*3 + 0] = f0;
    res_s[h*176 + 144 + p*3 + 1] = f1;
    res_s[h*176 + 144 + p*3 + 2] = f2;
    res_s[h*176 + 168 + p] = sqrtf(f0*f0 + f1*f1 + f2*f2 + 1e-12f);
  }
  __syncthreads();
  float4* rw4 = (float4*)(res_w + (size_t)n*2112);
  const float4* rs4 = (const float4*)res_s;
  for (int e4 = tid; e4 < 528; e4 += 256) rw4[e4] = rs4[e4];
}

// ---------------------------------------------------------------------------
// K3: out = res(512x2112) @ out_k(2112x384), split-K by 8 into partials.
// ---------------------------------------------------------------------------
__global__ __launch_bounds__(256) void k3_gemm(
    const float* __restrict__ A,    // [512][2112]
    const float* __restrict__ Bk,   // [2112][384]
    float* __restrict__ part)       // [8][512][384]
{
  const int tid = threadIdx.x;
  const int l0 = blockIdx.x*64, o0 = blockIdx.y*64, kz = blockIdx.z;
  const int tl = tid & 15, tc = tid >> 4;
  __shared__ float As[64*45];
  __shared__ __align__(16) float Bs[44*68];
  float acc[4][4] = {};
  const float4* A4 = (const float4*)A;
  const float4* B4 = (const float4*)Bk;
  float4* Bs4 = (float4*)Bs;

  for (int st = 0; st < 6; ++st) {
    const int k0 = kz*264 + st*44;
    __syncthreads();
    for (int e4 = tid; e4 < 704; e4 += 256) {       // A: 64 x 11 float4
      int r = e4/11, c4 = e4 - r*11;
      float4 v = A4[(size_t)(l0 + r)*528 + (k0 >> 2) + c4];
      float* d = &As[r*45 + 4*c4];
      d[0]=v.x; d[1]=v.y; d[2]=v.z; d[3]=v.w;
    }
    for (int e4 = tid; e4 < 704; e4 += 256) {       // B: 44 x 16 float4
      int k = e4 >> 4, c4 = e4 & 15;
      Bs4[k*17 + c4] = B4[(size_t)(k0 + k)*96 + (o0 >> 2) + c4];
    }
    __syncthreads();
    for (int k = 0; k < 44; ++k) {
      float4 b = Bs4[k*17 + tc];
      #pragma unroll
      for (int i = 0; i < 4; ++i) {
        float a = As[(4*tl + i)*45 + k];
        acc[i][0] += a*b.x; acc[i][1] += a*b.y; acc[i][2] += a*b.z; acc[i][3] += a*b.w;
      }
    }
  }
  float4* P4 = (float4*)part;
  #pragma unroll
  for (int i = 0; i < 4; ++i)
    P4[((size_t)kz*LQ + l0 + 4*tl + i)*96 + (o0 >> 2) + tc] =
        make_float4(acc[i][0], acc[i][1], acc[i][2], acc[i][3]);
}

__global__ __launch_bounds__(256) void k3_red(
    const float* __restrict__ part, const float* __restrict__ bias, float* __restrict__ out)
{
  int e4 = blockIdx.x*256 + threadIdx.x;   // 0..49151
  const float4* P4 = (const float4*)part;
  float4 s = {0,0,0,0};
  #pragma unroll
  for (int z = 0; z < 8; ++z) {
    float4 v = P4[(size_t)z*49152 + e4];
    s.x += v.x; s.y += v.y; s.z += v.z; s.w += v.w;
  }
  float4 b = ((const float4*)bias)[e4 % 96];
  s.x += b.x; s.y += b.y; s.z += b.z; s.w += b.w;
  ((float4*)out)[e4] = s;
}

// ---------------------------------------------------------------------------
extern "C" void kernel_launch(void* const* d_in, const int* in_sizes, int n_in,
                              void* d_out, int out_size, void* d_ws, size_t ws_size,
                              hipStream_t stream) {
  (void)in_sizes; (void)n_in; (void)out_size; (void)ws_size;
  const float* node  = (const float*)d_in[0];
  const float* Rm    = (const float*)d_in[1];
  const float* tv    = (const float*)d_in[2];
  const float* pairw = (const float*)d_in[3];
  const float* sq_k  = (const float*)d_in[4];
  const float* sk_k  = (const float*)d_in[5];
  const float* sv_k  = (const float*)d_in[6];
  const float* pq_k  = (const float*)d_in[7];
  const float* pk_k  = (const float*)d_in[8];
  const float* pv_k  = (const float*)d_in[9];
  const float* pr_k  = (const float*)d_in[10];
  const float* out_k = (const float*)d_in[11];
  const float* out_b = (const float*)d_in[12];
  const float* pwgt  = (const float*)d_in[13];

  float* ws = (float*)d_ws;
  float* sq_w  = ws;
  float* sk_w  = sq_w + (size_t)NH*LQ*16;
  float* sv_w  = sk_w + (size_t)NH*LQ*16;
  float* pq_w  = sv_w + (size_t)NH*LQ*16;
  float* pk_w  = pq_w + (size_t)NH*LQ*12;
  float* pv_w  = pk_w + (size_t)NH*LQ*12;
  float* res_w = pv_w + (size_t)NH*LQ*24;
  float* part_w = res_w + (size_t)LQ*2112;

  k1_proj<<<dim3(12,16,1), 256, 0, stream>>>(node, Rm, tv, sq_k, sk_k, sv_k,
                                             pq_k, pk_k, pv_k,
                                             sq_w, sk_w, sv_w, pq_w, pk_w, pv_w);
  k2_attn<<<dim3(512,1,1), 256, 0, stream>>>(pairw, Rm, tv, pr_k, pwgt,
                                             sq_w, sk_w, sv_w, pq_w, pk_w, pv_w,
                                             res_w);
  k3_gemm<<<dim3(8,6,8), 256, 0, stream>>>(res_w, out_k, part_w);
  k3_red<<<dim3(192,1,1), 256, 0, stream>>>(part_w, out_b, (float*)d_out);
}

// Round 3
// 180.916 us; speedup vs baseline: 1.8960x; 1.8960x over previous
//
#include <hip/hip_runtime.h>
#include <math.h>

#define LQ 512
#define NH 12
#define ND 384
#define PAIRC 128
#define RSQRT3 0.5773502691896258f
// sq scale: (1/4)*(1/sqrt(3))
#define SQSCALE 0.1443375672974065f
// point coef: 0.5/sqrt(18)/sqrt(3) = 0.5/sqrt(54)
#define PTCOEF 0.06804138174397717f

typedef __attribute__((ext_vector_type(8))) short short8v;
typedef __attribute__((ext_vector_type(4))) float f32x4;

__device__ __forceinline__ unsigned short f2bf(float f){
  unsigned int u = __float_as_uint(f);
  unsigned int r = (u + 0x7FFFu + ((u >> 16) & 1u)) >> 16;
  return (unsigned short)r;
}
__device__ __forceinline__ float bf2f(unsigned short u){
  return __uint_as_float(((unsigned int)u) << 16);
}
__device__ __forceinline__ void split2(float v, unsigned short* hi, unsigned short* lo){
  unsigned short h16 = f2bf(v);
  *hi = h16;
  *lo = f2bf(v - bf2f(h16));
}
__device__ __forceinline__ short8v cvt8(const float* p){
  float4 a = ((const float4*)p)[0];
  float4 b = ((const float4*)p)[1];
  short8v s;
  s[0]=(short)f2bf(a.x); s[1]=(short)f2bf(a.y); s[2]=(short)f2bf(a.z); s[3]=(short)f2bf(a.w);
  s[4]=(short)f2bf(b.x); s[5]=(short)f2bf(b.y); s[6]=(short)f2bf(b.z); s[7]=(short)f2bf(b.w);
  return s;
}

// ---------------------------------------------------------------------------
// K1: projections (unchanged, verified round 1)
// ---------------------------------------------------------------------------
__global__ __launch_bounds__(256) void k1_proj(
    const float* __restrict__ node, const float* __restrict__ Rm, const float* __restrict__ tv,
    const float* __restrict__ sq_k, const float* __restrict__ sk_k, const float* __restrict__ sv_k,
    const float* __restrict__ pq_k, const float* __restrict__ pk_k, const float* __restrict__ pv_k,
    float* __restrict__ sq_o, float* __restrict__ sk_o, float* __restrict__ sv_o,
    float* __restrict__ pq_o, float* __restrict__ pk_o, float* __restrict__ pv_o)
{
  const int h  = blockIdx.x;
  const int l0 = blockIdx.y * 32;
  const int tid = threadIdx.x;
  const int tl = tid & 15;
  const int tc = tid >> 4;
  const int ch0 = tc * 6;

  __shared__ float nl[32*33];
  __shared__ float wl[32*97];

  float acc0[6] = {0,0,0,0,0,0};
  float acc1[6] = {0,0,0,0,0,0};
  const float4* node4 = (const float4*)node;

  for (int kt = 0; kt < 12; ++kt) {
    const int k0 = kt * 32;
    __syncthreads();
    {
      int l = tid >> 3, k4 = tid & 7;
      float4 v = node4[(size_t)(l0 + l)*96 + kt*8 + k4];
      float* d = &nl[l*33 + 4*k4];
      d[0]=v.x; d[1]=v.y; d[2]=v.z; d[3]=v.w;
    }
    for (int e = tid; e < 3072; e += 256) {
      int k = e / 96, ch = e - k*96;
      float val;
      if (ch < 48) {
        const float* s = (ch < 16) ? sq_k : (ch < 32 ? sk_k : sv_k);
        val = s[((size_t)h*ND + k0 + k)*16 + (ch & 15)];
      } else if (ch < 72) {
        const float* s = (ch < 60) ? pq_k : pk_k;
        int col = ch - (ch < 60 ? 48 : 60);
        val = s[((size_t)h*ND + k0 + k)*12 + col];
      } else {
        val = pv_k[((size_t)h*ND + k0 + k)*24 + (ch - 72)];
      }
      wl[k*97 + ch] = val;
    }
    __syncthreads();
    for (int k = 0; k < 32; ++k) {
      float n0 = nl[(2*tl  )*33 + k];
      float n1 = nl[(2*tl+1)*33 + k];
      #pragma unroll
      for (int j = 0; j < 6; ++j) {
        float w = wl[k*97 + ch0 + j];
        acc0[j] += n0 * w;
        acc1[j] += n1 * w;
      }
    }
  }

  #pragma unroll
  for (int i = 0; i < 2; ++i) {
    const float* ac = i ? acc1 : acc0;
    const int l = l0 + 2*tl + i;
    if (ch0 < 48) {
      #pragma unroll
      for (int j = 0; j < 6; ++j) {
        int ch = ch0 + j; float v = ac[j];
        if (ch < 16)      sq_o[((size_t)h*LQ + l)*16 + ch       ] = v * SQSCALE;
        else if (ch < 32) sk_o[((size_t)h*LQ + l)*16 + (ch - 16)] = v;
        else              sv_o[((size_t)h*LQ + l)*16 + (ch - 32)] = v;
      }
    } else {
      float R_[9], t_[3];
      #pragma unroll
      for (int q = 0; q < 9; ++q) R_[q] = Rm[(size_t)l*9 + q];
      #pragma unroll
      for (int q = 0; q < 3; ++q) t_[q] = tv[(size_t)l*3 + q];
      #pragma unroll
      for (int b = 0; b < 6; b += 3) {
        int chb = ch0 + b;
        float x = ac[b], y = ac[b+1], z = ac[b+2];
        float g0 = x*R_[0] + y*R_[1] + z*R_[2] + t_[0];
        float g1 = x*R_[3] + y*R_[4] + z*R_[5] + t_[1];
        float g2 = x*R_[6] + y*R_[7] + z*R_[8] + t_[2];
        if (chb < 60) {
          size_t base = ((size_t)h*LQ + l)*12 + (chb - 48);
          pq_o[base] = g0; pq_o[base+1] = g1; pq_o[base+2] = g2;
        } else if (chb < 72) {
          size_t base = ((size_t)h*LQ + l)*12 + (chb - 60);
          pk_o[base] = g0; pk_o[base+1] = g1; pk_o[base+2] = g2;
        } else {
          size_t base = ((size_t)h*LQ + l)*24 + (chb - 72);
          pv_o[base] = g0; pv_o[base+1] = g1; pv_o[base+2] = g2;
        }
      }
    }
  }
}

// ---------------------------------------------------------------------------
// K1b: assemble bf16 hi/lo feature vectors (split-bf16 for f32-like precision)
// qf[h][l][32] = [sq(scaled), 2*cpw*pq(12), -cpw, 0,0,0]   (hi + lo arrays)
// kf[h][l][32] = [sk, pk(12), |pk|^2, 0,0,0]               (hi + lo arrays)
// vf[h][48][512] (transposed): rows 0..15 sv, 16..39 pv, 40..47 zero
// ---------------------------------------------------------------------------
__global__ __launch_bounds__(256) void k1b_feat(
    const float* __restrict__ sq_o, const float* __restrict__ sk_o, const float* __restrict__ sv_o,
    const float* __restrict__ pq_o, const float* __restrict__ pk_o, const float* __restrict__ pv_o,
    const float* __restrict__ pwgt,
    unsigned short* __restrict__ qfh, unsigned short* __restrict__ qfl,
    unsigned short* __restrict__ kfh, unsigned short* __restrict__ kfl,
    unsigned short* __restrict__ vf_w)
{
  int idx = blockIdx.x*256 + threadIdx.x;   // 12*512
  int h = idx >> 9, l = idx & 511;
  float x = pwgt[h];
  float sp = (x > 20.f) ? x : log1pf(__expf(x));
  float cpw = sp * PTCOEF;

  const float* sq = sq_o + ((size_t)h*LQ + l)*16;
  const float* sk = sk_o + ((size_t)h*LQ + l)*16;
  const float* sv = sv_o + ((size_t)h*LQ + l)*16;
  const float* pq = pq_o + ((size_t)h*LQ + l)*12;
  const float* pk = pk_o + ((size_t)h*LQ + l)*12;
  const float* pv = pv_o + ((size_t)h*LQ + l)*24;

  const size_t base = ((size_t)h*LQ + l)*32;
  float pkn = 0.f;
  #pragma unroll
  for (int j = 0; j < 12; ++j) { float v = pk[j]; pkn += v*v; }
  #pragma unroll
  for (int j = 0; j < 16; ++j) {
    split2(sq[j], &qfh[base+j], &qfl[base+j]);
    split2(sk[j], &kfh[base+j], &kfl[base+j]);
  }
  #pragma unroll
  for (int j = 0; j < 12; ++j) {
    split2(pq[j]*(2.f*cpw), &qfh[base+16+j], &qfl[base+16+j]);
    split2(pk[j],           &kfh[base+16+j], &kfl[base+16+j]);
  }
  split2(-cpw, &qfh[base+28], &qfl[base+28]);
  split2(pkn,  &kfh[base+28], &kfl[base+28]);
  #pragma unroll
  for (int j = 29; j < 32; ++j) {
    qfh[base+j]=0; qfl[base+j]=0; kfh[base+j]=0; kfl[base+j]=0;
  }

  #pragma unroll
  for (int v = 0; v < 48; ++v) {
    float val = (v < 16) ? sv[v] : (v < 40 ? pv[v-16] : 0.f);
    vf_w[((size_t)h*48 + v)*LQ + l] = f2bf(val);
  }
}

// ---------------------------------------------------------------------------
// K_qk: pre-logits via 3x MFMA hi/lo. pre[h][n][m] (f32 out).
// pre = qh.kh + qh.kl + ql.kh  ~ f32 precision of q.k
// ---------------------------------------------------------------------------
__global__ __launch_bounds__(256) void k_qk(
    const unsigned short* __restrict__ qfh, const unsigned short* __restrict__ qfl,
    const unsigned short* __restrict__ kfh, const unsigned short* __restrict__ kfl,
    float* __restrict__ pre_w)
{
  const int n0 = blockIdx.x*64, m0 = blockIdx.y*64, h = blockIdx.z;
  const int tid = threadIdx.x, lane = tid & 63, w = tid >> 6;
  const int lh = lane & 15, lg = lane >> 4;

  const size_t qoff = ((size_t)h*LQ + n0 + w*16 + lh)*32 + lg*8;
  short8v ah = *(const short8v*)(qfh + qoff);
  short8v al = *(const short8v*)(qfl + qoff);
  #pragma unroll
  for (int ms = 0; ms < 4; ++ms) {
    const size_t koff = ((size_t)h*LQ + m0 + ms*16 + lh)*32 + lg*8;
    short8v bh = *(const short8v*)(kfh + koff);
    short8v bl = *(const short8v*)(kfl + koff);
    f32x4 d = {0.f,0.f,0.f,0.f};
    d = __builtin_amdgcn_mfma_f32_16x16x32_bf16(ah, bh, d, 0, 0, 0);
    d = __builtin_amdgcn_mfma_f32_16x16x32_bf16(ah, bl, d, 0, 0, 0);
    d = __builtin_amdgcn_mfma_f32_16x16x32_bf16(al, bh, d, 0, 0, 0);
    #pragma unroll
    for (int r = 0; r < 4; ++r) {
      int nn = n0 + w*16 + lg*4 + r;
      pre_w[((size_t)h*LQ + nn)*LQ + m0 + ms*16 + lh] = d[r];
    }
  }
}

// ---------------------------------------------------------------------------
// K2F: fused pairwise logits + softmax + pairwise PV. One block per n.
// LDS: pwlds [c=128][m=512] bf16 swizzled (128KB); prelds [12][520] f32
// (aliased by plds [16][520] bf16 after barrier B3); red partials.
// ---------------------------------------------------------------------------
#define PRE_STR 520
__global__ __launch_bounds__(256) void k2f_attn(
    const float* __restrict__ pw, const float* __restrict__ pr_k,
    const float* __restrict__ pre_w,
    unsigned short* __restrict__ attn_w, float* __restrict__ res_w)
{
  const int n = blockIdx.x;
  const int tid = threadIdx.x, lane = tid & 63, w = tid >> 6;
  const int lh = lane & 15, lg = lane >> 4;

  __shared__ unsigned short pwlds[128 * 512];       // 128 KB
  __shared__ __align__(16) float prelds[12 * PRE_STR + 8];
  __shared__ float red[2][4][16];

  unsigned short* plds = (unsigned short*)prelds;   // [16][520] bf16

  // pr B-frags (constant): B[k=c][col=h]
  short8v prf[4];
  #pragma unroll
  for (int ks = 0; ks < 4; ++ks) {
    short8v s = {0,0,0,0,0,0,0,0};
    if (lh < 12) {
      const float* p = pr_k + (size_t)lh*PAIRC + ks*32 + lg*8;
      #pragma unroll
      for (int j = 0; j < 8; ++j) s[j] = (short)f2bf(p[j] * RSQRT3);
    }
    prf[ks] = s;
  }

  // stage pre (f32)
  const float4* p4 = (const float4*)pre_w;
  #pragma unroll
  for (int i = 0; i < 6; ++i) {
    int c4 = tid + 256*i;                 // 0..1535
    int h = c4 >> 7, m4 = (c4 & 127);
    float4 v = p4[((size_t)h*LQ + n)*128 + m4];
    *(float4*)(prelds + h*PRE_STR + m4*4) = v;
  }

  // stream pairwise: global -> (bf16) -> MFMA A-frag + swizzled LDS
  f32x4 acc[8];
  #pragma unroll
  for (int f = 0; f < 8; ++f) { f32x4 z = {0.f,0.f,0.f,0.f}; acc[f] = z; }

  const int mbase = w * 128;
  #pragma unroll 2
  for (int f = 0; f < 8; ++f) {
    const int m = mbase + f*16 + lh;
    const float* prow = pw + ((size_t)n*LQ + m)*PAIRC;
    #pragma unroll
    for (int ks = 0; ks < 4; ++ks) {
      const int c0 = ks*32 + lg*8;
      short8v a = cvt8(prow + c0);
      acc[f] = __builtin_amdgcn_mfma_f32_16x16x32_bf16(a, prf[ks], acc[f], 0, 0, 0);
      #pragma unroll
      for (int j = 0; j < 8; ++j) {
        int c = c0 + j;
        int byteoff = c*1024 + (((((m>>3) ^ (c & 7)) << 4)) | ((m & 7)*2));
        *(unsigned short*)((char*)pwlds + byteoff) = (unsigned short)a[j];
      }
    }
  }
  __syncthreads();   // B1: prelds + pwlds ready

  // logits for head lh at m = mbase + f*16 + lg*4 + r
  float lgt[8][4];
  float mx = -INFINITY;
  #pragma unroll
  for (int f = 0; f < 8; ++f) {
    #pragma unroll
    for (int r = 0; r < 4; ++r) {
      int m = mbase + f*16 + lg*4 + r;
      float v = acc[f][r];
      if (lh < 12) v += prelds[lh*PRE_STR + m];
      lgt[f][r] = v;
      mx = fmaxf(mx, v);
    }
  }
  mx = fmaxf(mx, __shfl_xor(mx, 16));
  mx = fmaxf(mx, __shfl_xor(mx, 32));
  if (lane < 16) red[0][w][lane] = mx;
  __syncthreads();   // B2
  float M = fmaxf(fmaxf(red[0][0][lh], red[0][1][lh]),
                  fmaxf(red[0][2][lh], red[0][3][lh]));
  float sm = 0.f;
  #pragma unroll
  for (int f = 0; f < 8; ++f) {
    #pragma unroll
    for (int r = 0; r < 4; ++r) {
      float e = __expf(lgt[f][r] - M);
      lgt[f][r] = e;
      sm += e;
    }
  }
  sm += __shfl_xor(sm, 16);
  sm += __shfl_xor(sm, 32);
  if (lane < 16) red[1][w][lane] = sm;
  __syncthreads();   // B3
  float S = red[1][0][lh] + red[1][1][lh] + red[1][2][lh] + red[1][3][lh];
  float rinv = 1.f / S;
  #pragma unroll
  for (int f = 0; f < 8; ++f) {
    #pragma unroll
    for (int r = 0; r < 4; ++r) {
      int m = mbase + f*16 + lg*4 + r;
      plds[lh*PRE_STR + m] = f2bf(lgt[f][r] * rinv);
    }
  }
  __syncthreads();   // B4: plds ready (prelds fully dead)

  // attn global write (bf16) for K5
  #pragma unroll
  for (int i = 0; i < 3; ++i) {
    int c8 = tid + 256*i;                 // 0..767 -> 12 heads x 64 chunks
    int h = c8 >> 6, m = (c8 & 63) * 8;
    short8v v = *(const short8v*)(plds + h*PRE_STR + m);
    *(short8v*)(attn_w + ((size_t)h*LQ + n)*LQ + m) = v;
  }

  // PV: out[h][c] = sum_m P[h][m] * pw[m][c]; wave w owns c in [32w, 32w+32)
  f32x4 o0 = {0.f,0.f,0.f,0.f}, o1 = {0.f,0.f,0.f,0.f};
  const int c0 = w*32 + lh;
  const int c1 = c0 + 16;
  #pragma unroll 4
  for (int ks = 0; ks < 16; ++ks) {
    short8v a = *(const short8v*)(plds + lh*PRE_STR + ks*32 + lg*8);
    int blk = ks*4 + lg;
    short8v b0 = *(const short8v*)((char*)pwlds + c0*1024 + ((blk ^ (c0 & 7)) << 4));
    short8v b1 = *(const short8v*)((char*)pwlds + c1*1024 + ((blk ^ (c1 & 7)) << 4));
    o0 = __builtin_amdgcn_mfma_f32_16x16x32_bf16(a, b0, o0, 0, 0, 0);
    o1 = __builtin_amdgcn_mfma_f32_16x16x32_bf16(a, b1, o1, 0, 0, 0);
  }
  #pragma unroll
  for (int r = 0; r < 4; ++r) {
    int h = lg*4 + r;
    if (h < 12) {
      float* d = res_w + (size_t)n*2112 + h*176 + 16;
      d[c0] = o0[r];
      d[c1] = o1[r];
    }
  }
}

// ---------------------------------------------------------------------------
// K5: scaler + point PV from materialized attn. Per head h:
// out[n][v] = sum_m attn[h][n][m] * vf[h][v][m],  v in [0,48)
// ---------------------------------------------------------------------------
__global__ __launch_bounds__(256) void k5_svpv(
    const unsigned short* __restrict__ attn_w, const unsigned short* __restrict__ vf_w,
    float* __restrict__ res_w, float* __restrict__ po_w)
{
  const int n0 = blockIdx.x*64, h = blockIdx.y;
  const int tid = threadIdx.x, lane = tid & 63, w = tid >> 6;
  const int lh = lane & 15, lg = lane >> 4;
  const int nb = n0 + w*16;

  f32x4 acc[3];
  #pragma unroll
  for (int v = 0; v < 3; ++v) { f32x4 z = {0.f,0.f,0.f,0.f}; acc[v] = z; }

  #pragma unroll 4
  for (int ks = 0; ks < 16; ++ks) {
    short8v a = *(const short8v*)(attn_w + ((size_t)h*LQ + nb + lh)*LQ + ks*32 + lg*8);
    #pragma unroll
    for (int v = 0; v < 3; ++v) {
      short8v b = *(const short8v*)(vf_w + ((size_t)h*48 + v*16 + lh)*LQ + ks*32 + lg*8);
      acc[v] = __builtin_amdgcn_mfma_f32_16x16x32_bf16(a, b, acc[v], 0, 0, 0);
    }
  }
  #pragma unroll
  for (int v = 0; v < 3; ++v) {
    #pragma unroll
    for (int r = 0; r < 4; ++r) {
      int col = v*16 + lh;
      int nn = nb + lg*4 + r;
      float val = acc[v][r];
      if (col < 16)      res_w[(size_t)nn*2112 + h*176 + col] = val;
      else if (col < 40) po_w[((size_t)h*LQ + nn)*24 + col - 16] = val;
    }
  }
}

// ---------------------------------------------------------------------------
// K6: point output frame transform + norms
// ---------------------------------------------------------------------------
__global__ __launch_bounds__(256) void k6_point(
    const float* __restrict__ po_w, const float* __restrict__ Rm, const float* __restrict__ tv,
    float* __restrict__ res_w)
{
  int idx = blockIdx.x*256 + threadIdx.x;   // 12*512*8
  int h = idx / (LQ*8);
  int rem = idx - h*(LQ*8);
  int n = rem >> 3, p = rem & 7;
  const float* po = po_w + ((size_t)h*LQ + n)*24 + p*3;
  float v0 = po[0] - tv[(size_t)n*3+0];
  float v1 = po[1] - tv[(size_t)n*3+1];
  float v2 = po[2] - tv[(size_t)n*3+2];
  const float* R_ = Rm + (size_t)n*9;
  float f0 = v0*R_[0] + v1*R_[3] + v2*R_[6];
  float f1 = v0*R_[1] + v1*R_[4] + v2*R_[7];
  float f2 = v0*R_[2] + v1*R_[5] + v2*R_[8];
  float* d = res_w + (size_t)n*2112 + h*176;
  d[144 + p*3 + 0] = f0;
  d[144 + p*3 + 1] = f1;
  d[144 + p*3 + 2] = f2;
  d[168 + p] = sqrtf(f0*f0 + f1*f1 + f2*f2 + 1e-12f);
}

// ---------------------------------------------------------------------------
// K3: out = res(512x2112) @ out_k(2112x384), split-K by 8 (unchanged)
// ---------------------------------------------------------------------------
__global__ __launch_bounds__(256) void k3_gemm(
    const float* __restrict__ A, const float* __restrict__ Bk, float* __restrict__ part)
{
  const int tid = threadIdx.x;
  const int l0 = blockIdx.x*64, o0 = blockIdx.y*64, kz = blockIdx.z;
  const int tl = tid & 15, tc = tid >> 4;
  __shared__ float As[64*45];
  __shared__ __align__(16) float Bs[44*68];
  float acc[4][4] = {};
  const float4* A4 = (const float4*)A;
  const float4* B4 = (const float4*)Bk;
  float4* Bs4 = (float4*)Bs;

  for (int st = 0; st < 6; ++st) {
    const int k0 = kz*264 + st*44;
    __syncthreads();
    for (int e4 = tid; e4 < 704; e4 += 256) {
      int r = e4/11, c4 = e4 - r*11;
      float4 v = A4[(size_t)(l0 + r)*528 + (k0 >> 2) + c4];
      float* d = &As[r*45 + 4*c4];
      d[0]=v.x; d[1]=v.y; d[2]=v.z; d[3]=v.w;
    }
    for (int e4 = tid; e4 < 704; e4 += 256) {
      int k = e4 >> 4, c4 = e4 & 15;
      Bs4[k*17 + c4] = B4[(size_t)(k0 + k)*96 + (o0 >> 2) + c4];
    }
    __syncthreads();
    for (int k = 0; k < 44; ++k) {
      float4 b = Bs4[k*17 + tc];
      #pragma unroll
      for (int i = 0; i < 4; ++i) {
        float a = As[(4*tl + i)*45 + k];
        acc[i][0] += a*b.x; acc[i][1] += a*b.y; acc[i][2] += a*b.z; acc[i][3] += a*b.w;
      }
    }
  }
  float4* P4 = (float4*)part;
  #pragma unroll
  for (int i = 0; i < 4; ++i)
    P4[((size_t)kz*LQ + l0 + 4*tl + i)*96 + (o0 >> 2) + tc] =
        make_float4(acc[i][0], acc[i][1], acc[i][2], acc[i][3]);
}

__global__ __launch_bounds__(256) void k3_red(
    const float* __restrict__ part, const float* __restrict__ bias, float* __restrict__ out)
{
  int e4 = blockIdx.x*256 + threadIdx.x;
  const float4* P4 = (const float4*)part;
  float4 s = {0,0,0,0};
  #pragma unroll
  for (int z = 0; z < 8; ++z) {
    float4 v = P4[(size_t)z*49152 + e4];
    s.x += v.x; s.y += v.y; s.z += v.z; s.w += v.w;
  }
  float4 b = ((const float4*)bias)[e4 % 96];
  s.x += b.x; s.y += b.y; s.z += b.z; s.w += b.w;
  ((float4*)out)[e4] = s;
}

// ---------------------------------------------------------------------------
extern "C" void kernel_launch(void* const* d_in, const int* in_sizes, int n_in,
                              void* d_out, int out_size, void* d_ws, size_t ws_size,
                              hipStream_t stream) {
  (void)in_sizes; (void)n_in; (void)out_size; (void)ws_size;
  const float* node  = (const float*)d_in[0];
  const float* Rm    = (const float*)d_in[1];
  const float* tv    = (const float*)d_in[2];
  const float* pairw = (const float*)d_in[3];
  const float* sq_k  = (const float*)d_in[4];
  const float* sk_k  = (const float*)d_in[5];
  const float* sv_k  = (const float*)d_in[6];
  const float* pq_k  = (const float*)d_in[7];
  const float* pk_k  = (const float*)d_in[8];
  const float* pv_k  = (const float*)d_in[9];
  const float* pr_k  = (const float*)d_in[10];
  const float* out_k = (const float*)d_in[11];
  const float* out_b = (const float*)d_in[12];
  const float* pwgt  = (const float*)d_in[13];

  float* ws = (float*)d_ws;
  // float-unit offsets
  float* sq_w  = ws + 0;              // 98304
  float* sk_w  = ws + 98304;          // 98304
  float* sv_w  = ws + 196608;         // 98304
  float* pq_w  = ws + 294912;         // 73728
  float* pk_w  = ws + 368640;         // 73728
  float* pv_w  = ws + 442368;         // 147456
  float* res_w = ws + 589824;         // 1081344 -> ends 1671168
  unsigned short* qfh = (unsigned short*)(ws + 1671168);   // 98304 f each
  unsigned short* qfl = (unsigned short*)(ws + 1769472);
  unsigned short* kfh = (unsigned short*)(ws + 1867776);
  unsigned short* kfl = (unsigned short*)(ws + 1966080);   // ends 2064384
  float* po_w  = ws + 1867776;        // ALIAS over kfh/kfl (dead after k_qk)
  unsigned short* vf_w = (unsigned short*)(ws + 2064384);  // 147456 f
  unsigned short* attn_w = (unsigned short*)(ws + 2211840);// 1572864 f -> 3784704
  float* pre_w = ws + 3784704;        // 3145728 f -> 6930432
  float* part_w = ws + 3784704;       // ALIAS over pre (dead after k2f)

  k1_proj<<<dim3(12,16,1), 256, 0, stream>>>(node, Rm, tv, sq_k, sk_k, sv_k,
                                             pq_k, pk_k, pv_k,
                                             sq_w, sk_w, sv_w, pq_w, pk_w, pv_w);
  k1b_feat<<<dim3(24,1,1), 256, 0, stream>>>(sq_w, sk_w, sv_w, pq_w, pk_w, pv_w,
                                             pwgt, qfh, qfl, kfh, kfl, vf_w);
  k_qk<<<dim3(8,8,12), 256, 0, stream>>>(qfh, qfl, kfh, kfl, pre_w);
  k2f_attn<<<dim3(512,1,1), 256, 0, stream>>>(pairw, pr_k, pre_w, attn_w, res_w);
  k5_svpv<<<dim3(8,12,1), 256, 0, stream>>>(attn_w, vf_w, res_w, po_w);
  k6_point<<<dim3(192,1,1), 256, 0, stream>>>(po_w, Rm, tv, res_w);
  k3_gemm<<<dim3(8,6,8), 256, 0, stream>>>(res_w, out_k, part_w);
  k3_red<<<dim3(192,1,1), 256, 0, stream>>>(part_w, out_b, (float*)d_out);
}

// Round 4
// 126.804 us; speedup vs baseline: 2.7051x; 1.4267x over previous
//
#include <hip/hip_runtime.h>
#include <math.h>

#define LQ 512
#define NH 12
#define ND 384
#define PAIRC 128
#define RSQRT3 0.5773502691896258f
// sq scale: (1/4)*(1/sqrt(3))
#define SQSCALE 0.1443375672974065f
// point coef: 0.5/sqrt(18)/sqrt(3) = 0.5/sqrt(54)
#define PTCOEF 0.06804138174397717f

typedef __attribute__((ext_vector_type(8))) short short8v;
typedef __attribute__((ext_vector_type(4))) float f32x4;

__device__ __forceinline__ unsigned short f2bf(float f){
  unsigned int u = __float_as_uint(f);
  unsigned int r = (u + 0x7FFFu + ((u >> 16) & 1u)) >> 16;
  return (unsigned short)r;
}
__device__ __forceinline__ float bf2f(unsigned short u){
  return __uint_as_float(((unsigned int)u) << 16);
}
__device__ __forceinline__ void split2(float v, unsigned short* hi, unsigned short* lo){
  unsigned short h16 = f2bf(v);
  *hi = h16;
  *lo = f2bf(v - bf2f(h16));
}
__device__ __forceinline__ short8v cvt8(const float* p){
  float4 a = ((const float4*)p)[0];
  float4 b = ((const float4*)p)[1];
  short8v s;
  s[0]=(short)f2bf(a.x); s[1]=(short)f2bf(a.y); s[2]=(short)f2bf(a.z); s[3]=(short)f2bf(a.w);
  s[4]=(short)f2bf(b.x); s[5]=(short)f2bf(b.y); s[6]=(short)f2bf(b.z); s[7]=(short)f2bf(b.w);
  return s;
}

// ---------------------------------------------------------------------------
// K0: pack node + concatenated weights into bf16 hi/lo.
// W layout: [h][ch=96][k=384]; ch: 0..15 sq(*SQSCALE) | 16..31 sk | 32..47 sv
//           | 48..59 pq | 60..71 pk | 72..95 pv
// ---------------------------------------------------------------------------
__global__ __launch_bounds__(256) void k0_pack(
    const float* __restrict__ node,
    const float* __restrict__ sq_k, const float* __restrict__ sk_k, const float* __restrict__ sv_k,
    const float* __restrict__ pq_k, const float* __restrict__ pk_k, const float* __restrict__ pv_k,
    unsigned short* __restrict__ nh, unsigned short* __restrict__ nl,
    unsigned short* __restrict__ Wh, unsigned short* __restrict__ Wl)
{
  int idx = blockIdx.x*256 + threadIdx.x;     // 0 .. 638975
  if (idx < 196608) {
    unsigned short hi, lo;
    split2(node[idx], &hi, &lo);
    nh[idx] = hi; nl[idx] = lo;
  } else {
    int widx = idx - 196608;                  // = (h*96+ch)*384 + k
    int h = widx / 36864;
    int rem = widx - h*36864;
    int ch = rem / 384;
    int k = rem - ch*384;
    float val;
    if (ch < 16)      val = sq_k[((size_t)h*ND + k)*16 + ch] * SQSCALE;
    else if (ch < 32) val = sk_k[((size_t)h*ND + k)*16 + ch - 16];
    else if (ch < 48) val = sv_k[((size_t)h*ND + k)*16 + ch - 32];
    else if (ch < 60) val = pq_k[((size_t)h*ND + k)*12 + ch - 48];
    else if (ch < 72) val = pk_k[((size_t)h*ND + k)*12 + ch - 60];
    else              val = pv_k[((size_t)h*ND + k)*24 + ch - 72];
    unsigned short hi, lo;
    split2(val, &hi, &lo);
    Wh[widx] = hi; Wl[widx] = lo;
  }
}

// ---------------------------------------------------------------------------
// K1: projection GEMM via hi/lo MFMA. One wave per block.
// block (lt, h, kz): rows lt*16..+16, cols h*96..+96, K half kz.
// proj[kz][h][l][96] partials (summed in k1b).
// ---------------------------------------------------------------------------
__global__ __launch_bounds__(64) void k1_mfma(
    const unsigned short* __restrict__ nh, const unsigned short* __restrict__ nl,
    const unsigned short* __restrict__ Wh, const unsigned short* __restrict__ Wl,
    float* __restrict__ proj)
{
  const int lt = blockIdx.x, h = blockIdx.y, kz = blockIdx.z;
  const int lane = threadIdx.x;
  const int lh = lane & 15, lg = lane >> 4;

  f32x4 acc[6];
  #pragma unroll
  for (int ms = 0; ms < 6; ++ms) { f32x4 z = {0.f,0.f,0.f,0.f}; acc[ms] = z; }

  const unsigned short* nrh = nh + ((size_t)lt*16 + lh)*384;
  const unsigned short* nrl = nl + ((size_t)lt*16 + lh)*384;
  #pragma unroll 2
  for (int ks = 0; ks < 6; ++ks) {
    const int koff = kz*192 + ks*32 + lg*8;
    short8v ah = *(const short8v*)(nrh + koff);
    short8v al = *(const short8v*)(nrl + koff);
    #pragma unroll
    for (int ms = 0; ms < 6; ++ms) {
      const size_t wo = ((size_t)h*96 + ms*16 + lh)*384 + koff;
      short8v bh = *(const short8v*)(Wh + wo);
      short8v bl = *(const short8v*)(Wl + wo);
      acc[ms] = __builtin_amdgcn_mfma_f32_16x16x32_bf16(ah, bh, acc[ms], 0, 0, 0);
      acc[ms] = __builtin_amdgcn_mfma_f32_16x16x32_bf16(ah, bl, acc[ms], 0, 0, 0);
      acc[ms] = __builtin_amdgcn_mfma_f32_16x16x32_bf16(al, bh, acc[ms], 0, 0, 0);
    }
  }
  float* dst = proj + (size_t)kz*589824 + ((size_t)h*LQ + lt*16)*96;
  #pragma unroll
  for (int ms = 0; ms < 6; ++ms) {
    #pragma unroll
    for (int r = 0; r < 4; ++r)
      dst[(lg*4 + r)*96 + ms*16 + lh] = acc[ms][r];
  }
}

// ---------------------------------------------------------------------------
// K1b: sum proj partials, rotate point channels, assemble bf16 hi/lo features.
// qf[h][l][32] = [sq(scaled), 2*cpw*pq(12), -cpw, 0,0,0]   (hi + lo arrays)
// kf[h][l][32] = [sk, pk(12), |pk|^2, 0,0,0]               (hi + lo arrays)
// vf[h][48][512] (transposed): rows 0..15 sv, 16..39 pv, 40..47 zero
// ---------------------------------------------------------------------------
__global__ __launch_bounds__(256) void k1b_feat(
    const float* __restrict__ proj, const float* __restrict__ Rm, const float* __restrict__ tv,
    const float* __restrict__ pwgt,
    unsigned short* __restrict__ qfh, unsigned short* __restrict__ qfl,
    unsigned short* __restrict__ kfh, unsigned short* __restrict__ kfl,
    unsigned short* __restrict__ vf_w)
{
  int idx = blockIdx.x*256 + threadIdx.x;   // 12*512
  int h = idx >> 9, l = idx & 511;
  float x = pwgt[h];
  float sp = (x > 20.f) ? x : log1pf(__expf(x));
  float cpw = sp * PTCOEF;

  float v[96];
  {
    const float4* a = (const float4*)(proj + ((size_t)h*LQ + l)*96);
    const float4* b = (const float4*)(proj + 589824 + ((size_t)h*LQ + l)*96);
    #pragma unroll
    for (int i = 0; i < 24; ++i) {
      float4 p = a[i], q = b[i];
      v[4*i+0] = p.x + q.x; v[4*i+1] = p.y + q.y;
      v[4*i+2] = p.z + q.z; v[4*i+3] = p.w + q.w;
    }
  }
  float R_[9], t_[3];
  #pragma unroll
  for (int q = 0; q < 9; ++q) R_[q] = Rm[(size_t)l*9 + q];
  #pragma unroll
  for (int q = 0; q < 3; ++q) t_[q] = tv[(size_t)l*3 + q];
  #pragma unroll
  for (int p = 0; p < 16; ++p) {           // 16 triples: pq(4), pk(4), pv(8)
    float x0 = v[48+p*3], y0 = v[48+p*3+1], z0 = v[48+p*3+2];
    v[48+p*3+0] = x0*R_[0] + y0*R_[1] + z0*R_[2] + t_[0];
    v[48+p*3+1] = x0*R_[3] + y0*R_[4] + z0*R_[5] + t_[1];
    v[48+p*3+2] = x0*R_[6] + y0*R_[7] + z0*R_[8] + t_[2];
  }

  const size_t base = ((size_t)h*LQ + l)*32;
  float pkn = 0.f;
  #pragma unroll
  for (int j = 0; j < 12; ++j) { float w = v[60+j]; pkn += w*w; }
  #pragma unroll
  for (int j = 0; j < 16; ++j) {
    split2(v[j],    &qfh[base+j], &qfl[base+j]);
    split2(v[16+j], &kfh[base+j], &kfl[base+j]);
  }
  #pragma unroll
  for (int j = 0; j < 12; ++j) {
    split2(v[48+j]*(2.f*cpw), &qfh[base+16+j], &qfl[base+16+j]);
    split2(v[60+j],           &kfh[base+16+j], &kfl[base+16+j]);
  }
  split2(-cpw, &qfh[base+28], &qfl[base+28]);
  split2(pkn,  &kfh[base+28], &kfl[base+28]);
  #pragma unroll
  for (int j = 29; j < 32; ++j) {
    qfh[base+j]=0; qfl[base+j]=0; kfh[base+j]=0; kfl[base+j]=0;
  }

  #pragma unroll
  for (int vv = 0; vv < 48; ++vv) {
    float val = (vv < 16) ? v[32+vv] : (vv < 40 ? v[72+vv-16] : 0.f);
    vf_w[((size_t)h*48 + vv)*LQ + l] = f2bf(val);
  }
}

// ---------------------------------------------------------------------------
// K_qk: pre-logits via 3x MFMA hi/lo. pre[h][n][m] (f32 out).
// ---------------------------------------------------------------------------
__global__ __launch_bounds__(256) void k_qk(
    const unsigned short* __restrict__ qfh, const unsigned short* __restrict__ qfl,
    const unsigned short* __restrict__ kfh, const unsigned short* __restrict__ kfl,
    float* __restrict__ pre_w)
{
  const int n0 = blockIdx.x*64, m0 = blockIdx.y*64, h = blockIdx.z;
  const int tid = threadIdx.x, lane = tid & 63, w = tid >> 6;
  const int lh = lane & 15, lg = lane >> 4;

  const size_t qoff = ((size_t)h*LQ + n0 + w*16 + lh)*32 + lg*8;
  short8v ah = *(const short8v*)(qfh + qoff);
  short8v al = *(const short8v*)(qfl + qoff);
  #pragma unroll
  for (int ms = 0; ms < 4; ++ms) {
    const size_t koff = ((size_t)h*LQ + m0 + ms*16 + lh)*32 + lg*8;
    short8v bh = *(const short8v*)(kfh + koff);
    short8v bl = *(const short8v*)(kfl + koff);
    f32x4 d = {0.f,0.f,0.f,0.f};
    d = __builtin_amdgcn_mfma_f32_16x16x32_bf16(ah, bh, d, 0, 0, 0);
    d = __builtin_amdgcn_mfma_f32_16x16x32_bf16(ah, bl, d, 0, 0, 0);
    d = __builtin_amdgcn_mfma_f32_16x16x32_bf16(al, bh, d, 0, 0, 0);
    #pragma unroll
    for (int r = 0; r < 4; ++r) {
      int nn = n0 + w*16 + lg*4 + r;
      pre_w[((size_t)h*LQ + nn)*LQ + m0 + ms*16 + lh] = d[r];
    }
  }
}

// ---------------------------------------------------------------------------
// K2F: fused pairwise logits + softmax + pairwise PV. One block per n.
// ---------------------------------------------------------------------------
#define PRE_STR 520
__global__ __launch_bounds__(256) void k2f_attn(
    const float* __restrict__ pw, const float* __restrict__ pr_k,
    const float* __restrict__ pre_w,
    unsigned short* __restrict__ attn_w, float* __restrict__ res_w)
{
  const int n = blockIdx.x;
  const int tid = threadIdx.x, lane = tid & 63, w = tid >> 6;
  const int lh = lane & 15, lg = lane >> 4;

  __shared__ unsigned short pwlds[128 * 512];       // 128 KB
  __shared__ __align__(16) float prelds[12 * PRE_STR + 8];
  __shared__ float red[2][4][16];

  unsigned short* plds = (unsigned short*)prelds;   // [16][520] bf16

  // pr B-frags (constant): B[k=c][col=h]
  short8v prf[4];
  #pragma unroll
  for (int ks = 0; ks < 4; ++ks) {
    short8v s = {0,0,0,0,0,0,0,0};
    if (lh < 12) {
      const float* p = pr_k + (size_t)lh*PAIRC + ks*32 + lg*8;
      #pragma unroll
      for (int j = 0; j < 8; ++j) s[j] = (short)f2bf(p[j] * RSQRT3);
    }
    prf[ks] = s;
  }

  // stage pre (f32)
  const float4* p4 = (const float4*)pre_w;
  #pragma unroll
  for (int i = 0; i < 6; ++i) {
    int c4 = tid + 256*i;                 // 0..1535
    int h = c4 >> 7, m4 = (c4 & 127);
    float4 v = p4[((size_t)h*LQ + n)*128 + m4];
    *(float4*)(prelds + h*PRE_STR + m4*4) = v;
  }

  // stream pairwise: global -> (bf16) -> MFMA A-frag + swizzled LDS
  f32x4 acc[8];
  #pragma unroll
  for (int f = 0; f < 8; ++f) { f32x4 z = {0.f,0.f,0.f,0.f}; acc[f] = z; }

  const int mbase = w * 128;
  #pragma unroll 2
  for (int f = 0; f < 8; ++f) {
    const int m = mbase + f*16 + lh;
    const float* prow = pw + ((size_t)n*LQ + m)*PAIRC;
    #pragma unroll
    for (int ks = 0; ks < 4; ++ks) {
      const int c0 = ks*32 + lg*8;
      short8v a = cvt8(prow + c0);
      acc[f] = __builtin_amdgcn_mfma_f32_16x16x32_bf16(a, prf[ks], acc[f], 0, 0, 0);
      #pragma unroll
      for (int j = 0; j < 8; ++j) {
        int c = c0 + j;
        int byteoff = c*1024 + (((((m>>3) ^ (c & 7)) << 4)) | ((m & 7)*2));
        *(unsigned short*)((char*)pwlds + byteoff) = (unsigned short)a[j];
      }
    }
  }
  __syncthreads();   // B1: prelds + pwlds ready

  // logits for head lh at m = mbase + f*16 + lg*4 + r
  float lgt[8][4];
  float mx = -INFINITY;
  #pragma unroll
  for (int f = 0; f < 8; ++f) {
    #pragma unroll
    for (int r = 0; r < 4; ++r) {
      int m = mbase + f*16 + lg*4 + r;
      float v = acc[f][r];
      if (lh < 12) v += prelds[lh*PRE_STR + m];
      lgt[f][r] = v;
      mx = fmaxf(mx, v);
    }
  }
  mx = fmaxf(mx, __shfl_xor(mx, 16));
  mx = fmaxf(mx, __shfl_xor(mx, 32));
  if (lane < 16) red[0][w][lane] = mx;
  __syncthreads();   // B2
  float M = fmaxf(fmaxf(red[0][0][lh], red[0][1][lh]),
                  fmaxf(red[0][2][lh], red[0][3][lh]));
  float sm = 0.f;
  #pragma unroll
  for (int f = 0; f < 8; ++f) {
    #pragma unroll
    for (int r = 0; r < 4; ++r) {
      float e = __expf(lgt[f][r] - M);
      lgt[f][r] = e;
      sm += e;
    }
  }
  sm += __shfl_xor(sm, 16);
  sm += __shfl_xor(sm, 32);
  if (lane < 16) red[1][w][lane] = sm;
  __syncthreads();   // B3
  float S = red[1][0][lh] + red[1][1][lh] + red[1][2][lh] + red[1][3][lh];
  float rinv = 1.f / S;
  #pragma unroll
  for (int f = 0; f < 8; ++f) {
    #pragma unroll
    for (int r = 0; r < 4; ++r) {
      int m = mbase + f*16 + lg*4 + r;
      plds[lh*PRE_STR + m] = f2bf(lgt[f][r] * rinv);
    }
  }
  __syncthreads();   // B4: plds ready (prelds fully dead)

  // attn global write (bf16) for K5
  #pragma unroll
  for (int i = 0; i < 3; ++i) {
    int c8 = tid + 256*i;                 // 0..767 -> 12 heads x 64 chunks
    int h = c8 >> 6, m = (c8 & 63) * 8;
    short8v v = *(const short8v*)(plds + h*PRE_STR + m);
    *(short8v*)(attn_w + ((size_t)h*LQ + n)*LQ + m) = v;
  }

  // PV: out[h][c] = sum_m P[h][m] * pw[m][c]; wave w owns c in [32w, 32w+32)
  f32x4 o0 = {0.f,0.f,0.f,0.f}, o1 = {0.f,0.f,0.f,0.f};
  const int c0 = w*32 + lh;
  const int c1 = c0 + 16;
  #pragma unroll 4
  for (int ks = 0; ks < 16; ++ks) {
    short8v a = *(const short8v*)(plds + lh*PRE_STR + ks*32 + lg*8);
    int blk = ks*4 + lg;
    short8v b0 = *(const short8v*)((char*)pwlds + c0*1024 + ((blk ^ (c0 & 7)) << 4));
    short8v b1 = *(const short8v*)((char*)pwlds + c1*1024 + ((blk ^ (c1 & 7)) << 4));
    o0 = __builtin_amdgcn_mfma_f32_16x16x32_bf16(a, b0, o0, 0, 0, 0);
    o1 = __builtin_amdgcn_mfma_f32_16x16x32_bf16(a, b1, o1, 0, 0, 0);
  }
  #pragma unroll
  for (int r = 0; r < 4; ++r) {
    int h = lg*4 + r;
    if (h < 12) {
      float* d = res_w + (size_t)n*2112 + h*176 + 16;
      d[c0] = o0[r];
      d[c1] = o1[r];
    }
  }
}

// ---------------------------------------------------------------------------
// K5: scaler + point PV from materialized attn.
// ---------------------------------------------------------------------------
__global__ __launch_bounds__(256) void k5_svpv(
    const unsigned short* __restrict__ attn_w, const unsigned short* __restrict__ vf_w,
    float* __restrict__ res_w, float* __restrict__ po_w)
{
  const int n0 = blockIdx.x*64, h = blockIdx.y;
  const int tid = threadIdx.x, lane = tid & 63, w = tid >> 6;
  const int lh = lane & 15, lg = lane >> 4;
  const int nb = n0 + w*16;

  f32x4 acc[3];
  #pragma unroll
  for (int v = 0; v < 3; ++v) { f32x4 z = {0.f,0.f,0.f,0.f}; acc[v] = z; }

  #pragma unroll 4
  for (int ks = 0; ks < 16; ++ks) {
    short8v a = *(const short8v*)(attn_w + ((size_t)h*LQ + nb + lh)*LQ + ks*32 + lg*8);
    #pragma unroll
    for (int v = 0; v < 3; ++v) {
      short8v b = *(const short8v*)(vf_w + ((size_t)h*48 + v*16 + lh)*LQ + ks*32 + lg*8);
      acc[v] = __builtin_amdgcn_mfma_f32_16x16x32_bf16(a, b, acc[v], 0, 0, 0);
    }
  }
  #pragma unroll
  for (int v = 0; v < 3; ++v) {
    #pragma unroll
    for (int r = 0; r < 4; ++r) {
      int col = v*16 + lh;
      int nn = nb + lg*4 + r;
      float val = acc[v][r];
      if (col < 16)      res_w[(size_t)nn*2112 + h*176 + col] = val;
      else if (col < 40) po_w[((size_t)h*LQ + nn)*24 + col - 16] = val;
    }
  }
}

// ---------------------------------------------------------------------------
// K6: point output frame transform + norms
// ---------------------------------------------------------------------------
__global__ __launch_bounds__(256) void k6_point(
    const float* __restrict__ po_w, const float* __restrict__ Rm, const float* __restrict__ tv,
    float* __restrict__ res_w)
{
  int idx = blockIdx.x*256 + threadIdx.x;   // 12*512*8
  int h = idx / (LQ*8);
  int rem = idx - h*(LQ*8);
  int n = rem >> 3, p = rem & 7;
  const float* po = po_w + ((size_t)h*LQ + n)*24 + p*3;
  float v0 = po[0] - tv[(size_t)n*3+0];
  float v1 = po[1] - tv[(size_t)n*3+1];
  float v2 = po[2] - tv[(size_t)n*3+2];
  const float* R_ = Rm + (size_t)n*9;
  float f0 = v0*R_[0] + v1*R_[3] + v2*R_[6];
  float f1 = v0*R_[1] + v1*R_[4] + v2*R_[7];
  float f2 = v0*R_[2] + v1*R_[5] + v2*R_[8];
  float* d = res_w + (size_t)n*2112 + h*176;
  d[144 + p*3 + 0] = f0;
  d[144 + p*3 + 1] = f1;
  d[144 + p*3 + 2] = f2;
  d[168 + p] = sqrtf(f0*f0 + f1*f1 + f2*f2 + 1e-12f);
}

// ---------------------------------------------------------------------------
// K3: out = res(512x2112) @ out_k(2112x384), split-K by 8 (unchanged)
// ---------------------------------------------------------------------------
__global__ __launch_bounds__(256) void k3_gemm(
    const float* __restrict__ A, const float* __restrict__ Bk, float* __restrict__ part)
{
  const int tid = threadIdx.x;
  const int l0 = blockIdx.x*64, o0 = blockIdx.y*64, kz = blockIdx.z;
  const int tl = tid & 15, tc = tid >> 4;
  __shared__ float As[64*45];
  __shared__ __align__(16) float Bs[44*68];
  float acc[4][4] = {};
  const float4* A4 = (const float4*)A;
  const float4* B4 = (const float4*)Bk;
  float4* Bs4 = (float4*)Bs;

  for (int st = 0; st < 6; ++st) {
    const int k0 = kz*264 + st*44;
    __syncthreads();
    for (int e4 = tid; e4 < 704; e4 += 256) {
      int r = e4/11, c4 = e4 - r*11;
      float4 v = A4[(size_t)(l0 + r)*528 + (k0 >> 2) + c4];
      float* d = &As[r*45 + 4*c4];
      d[0]=v.x; d[1]=v.y; d[2]=v.z; d[3]=v.w;
    }
    for (int e4 = tid; e4 < 704; e4 += 256) {
      int k = e4 >> 4, c4 = e4 & 15;
      Bs4[k*17 + c4] = B4[(size_t)(k0 + k)*96 + (o0 >> 2) + c4];
    }
    __syncthreads();
    for (int k = 0; k < 44; ++k) {
      float4 b = Bs4[k*17 + tc];
      #pragma unroll
      for (int i = 0; i < 4; ++i) {
        float a = As[(4*tl + i)*45 + k];
        acc[i][0] += a*b.x; acc[i][1] += a*b.y; acc[i][2] += a*b.z; acc[i][3] += a*b.w;
      }
    }
  }
  float4* P4 = (float4*)part;
  #pragma unroll
  for (int i = 0; i < 4; ++i)
    P4[((size_t)kz*LQ + l0 + 4*tl + i)*96 + (o0 >> 2) + tc] =
        make_float4(acc[i][0], acc[i][1], acc[i][2], acc[i][3]);
}

__global__ __launch_bounds__(256) void k3_red(
    const float* __restrict__ part, const float* __restrict__ bias, float* __restrict__ out)
{
  int e4 = blockIdx.x*256 + threadIdx.x;
  const float4* P4 = (const float4*)part;
  float4 s = {0,0,0,0};
  #pragma unroll
  for (int z = 0; z < 8; ++z) {
    float4 v = P4[(size_t)z*49152 + e4];
    s.x += v.x; s.y += v.y; s.z += v.z; s.w += v.w;
  }
  float4 b = ((const float4*)bias)[e4 % 96];
  s.x += b.x; s.y += b.y; s.z += b.z; s.w += b.w;
  ((float4*)out)[e4] = s;
}

// ---------------------------------------------------------------------------
extern "C" void kernel_launch(void* const* d_in, const int* in_sizes, int n_in,
                              void* d_out, int out_size, void* d_ws, size_t ws_size,
                              hipStream_t stream) {
  (void)in_sizes; (void)n_in; (void)out_size; (void)ws_size;
  const float* node  = (const float*)d_in[0];
  const float* Rm    = (const float*)d_in[1];
  const float* tv    = (const float*)d_in[2];
  const float* pairw = (const float*)d_in[3];
  const float* sq_k  = (const float*)d_in[4];
  const float* sk_k  = (const float*)d_in[5];
  const float* sv_k  = (const float*)d_in[6];
  const float* pq_k  = (const float*)d_in[7];
  const float* pk_k  = (const float*)d_in[8];
  const float* pv_k  = (const float*)d_in[9];
  const float* pr_k  = (const float*)d_in[10];
  const float* out_k = (const float*)d_in[11];
  const float* out_b = (const float*)d_in[12];
  const float* pwgt  = (const float*)d_in[13];

  float* ws = (float*)d_ws;
  // pre_w occupies [0, 3145728); the k1-stage scratch lives inside it
  // (dead before k_qk writes pre). part_w also aliases (dead-by-k3 rule).
  float* pre_w = ws + 0;                                   // 3145728 f
  unsigned short* nh   = (unsigned short*)(ws + 0);        // 196608 sh
  unsigned short* nl   = (unsigned short*)(ws + 98304);
  unsigned short* Wh   = (unsigned short*)(ws + 196608);   // 442368 sh
  unsigned short* Wl   = (unsigned short*)(ws + 417792);
  float* proj = ws + 638976;                               // 2 x 589824 f
  float* part_w = ws + 0;                                  // 1572864 f (alias pre)
  unsigned short* qfh = (unsigned short*)(ws + 3145728);
  unsigned short* qfl = (unsigned short*)(ws + 3244032);
  unsigned short* kfh = (unsigned short*)(ws + 3342336);
  unsigned short* kfl = (unsigned short*)(ws + 3440640);
  unsigned short* vf_w = (unsigned short*)(ws + 3538944);  // 294912 sh
  unsigned short* attn_w = (unsigned short*)(ws + 3686400);// 3145728 sh
  float* res_w = ws + 5259264;                             // 1081344 f
  float* po_w  = ws + 6340608;                             // 147456 f

  k0_pack<<<dim3(2496,1,1), 256, 0, stream>>>(node, sq_k, sk_k, sv_k, pq_k, pk_k, pv_k,
                                              nh, nl, Wh, Wl);
  k1_mfma<<<dim3(32,12,2), 64, 0, stream>>>(nh, nl, Wh, Wl, proj);
  k1b_feat<<<dim3(24,1,1), 256, 0, stream>>>(proj, Rm, tv, pwgt,
                                             qfh, qfl, kfh, kfl, vf_w);
  k_qk<<<dim3(8,8,12), 256, 0, stream>>>(qfh, qfl, kfh, kfl, pre_w);
  k2f_attn<<<dim3(512,1,1), 256, 0, stream>>>(pairw, pr_k, pre_w, attn_w, res_w);
  k5_svpv<<<dim3(8,12,1), 256, 0, stream>>>(attn_w, vf_w, res_w, po_w);
  k6_point<<<dim3(192,1,1), 256, 0, stream>>>(po_w, Rm, tv, res_w);
  k3_gemm<<<dim3(8,6,8), 256, 0, stream>>>(res_w, out_k, part_w);
  k3_red<<<dim3(192,1,1), 256, 0, stream>>>(part_w, out_b, (float*)d_out);
}